// Round 3
// baseline (583.166 us; speedup 1.0000x reference)
//
#include <hip/hip_runtime.h>

#define BATCH 262144
#define NBLK 256
#define NITER 16          // 4096 tiles / 256 blocks
#define ASTRIDE 264       // 528B row stride
#define BH 33554432       // B*H

typedef __attribute__((ext_vector_type(8))) short bf16x8;
typedef __attribute__((ext_vector_type(4))) float f32x4;
typedef __attribute__((ext_vector_type(8))) unsigned short u16x8;

__device__ __forceinline__ unsigned short f2bf(float f) {
  unsigned int u = __float_as_uint(f);
  u += 0x7fffu + ((u >> 16) & 1u);  // round-to-nearest-even
  return (unsigned short)(u >> 16);
}

__device__ __forceinline__ float fexp(float x) { return __builtin_amdgcn_exp2f(x * 1.44269504f); }
__device__ __forceinline__ float sigm(float x) { return __builtin_amdgcn_rcpf(1.f + fexp(-x)); }
__device__ __forceinline__ float ftanh(float x) { return 1.f - 2.f * __builtin_amdgcn_rcpf(1.f + fexp(2.f * x)); }

__global__ __launch_bounds__(512, 2) void lstm_fused(
    const float* __restrict__ X, const float* __restrict__ H0, const float* __restrict__ C0,
    const float* __restrict__ Wii, const float* __restrict__ Whi,
    const float* __restrict__ Wif, const float* __restrict__ Whf,
    const float* __restrict__ Wio, const float* __restrict__ Who,
    const float* __restrict__ Wig, const float* __restrict__ Whg,
    float* __restrict__ Out) {
  __shared__ __align__(16) unsigned short Abuf[2][64 * ASTRIDE];

  const int tid = threadIdx.x;
  const int wave = tid >> 6;
  const int lane = tid & 63;
  const int lrow = lane & 15;
  const int lk = (lane >> 4) * 8;       // k sub-offset within a 32-wide K tile
  const int hcol = wave * 16 + lrow;    // hidden column this lane produces

  const float* Wxp[4] = {Wii, Wif, Wio, Wig};
  const float* Whp[4] = {Whi, Whf, Who, Whg};

  // ---- load weight fragments once; resident in VGPR/AGPR for the whole kernel ----
  bf16x8 wf[4][8];
#pragma unroll
  for (int g = 0; g < 4; ++g) {
#pragma unroll
    for (int kk = 0; kk < 8; ++kk) {
      const int k = kk * 32 + lk;
      const float* src = (kk < 4) ? (Wxp[g] + hcol * 128 + k)
                                  : (Whp[g] + hcol * 128 + (k - 128));
      float4 lo = *(const float4*)src;
      float4 hi = *(const float4*)(src + 4);
      bf16x8 w;
      w[0] = (short)f2bf(lo.x); w[1] = (short)f2bf(lo.y);
      w[2] = (short)f2bf(lo.z); w[3] = (short)f2bf(lo.w);
      w[4] = (short)f2bf(hi.x); w[5] = (short)f2bf(hi.y);
      w[6] = (short)f2bf(hi.z); w[7] = (short)f2bf(hi.w);
      wf[g][kk] = w;
    }
  }

  // Staging registers (tile t+1 in flight during compute of t)
  float4 sx[4], sh[4];

  auto issue_loads = [&](int row0) {
#pragma unroll
    for (int j = 0; j < 2; ++j) {
      const int f = tid + j * 512;
      const int r = f >> 4;
      const int c = (f & 15) * 8;
      const float* px = X + (size_t)(row0 + r) * 128 + c;
      sx[j * 2 + 0] = *(const float4*)px;
      sx[j * 2 + 1] = *(const float4*)(px + 4);
      const float* ph = H0 + (size_t)(row0 + r) * 128 + c;
      sh[j * 2 + 0] = *(const float4*)ph;
      sh[j * 2 + 1] = *(const float4*)(ph + 4);
    }
  };

  auto issue_cv = [&](int row0, float (&cv)[16]) {
    const int rb = row0 + (lane >> 4) * 4;
#pragma unroll
    for (int mt = 0; mt < 4; ++mt)
#pragma unroll
      for (int j = 0; j < 4; ++j)
        cv[mt * 4 + j] = C0[(size_t)(rb + mt * 16 + j) * 128 + hcol];
  };

  float cv0[16], cv1[16];

  // body of one tile-iteration; ab = LDS buffer, cvR = this tile's C_prev,
  // cvW = destination for next tile's C_prev prefetch.
  auto body = [&](int it, unsigned short* ab, float (&cvR)[16], float (&cvW)[16]) {
    const int row0 = (blockIdx.x + it * NBLK) * 64;

    // ---- convert staged regs -> LDS (bf16), 16B writes ----
#pragma unroll
    for (int j = 0; j < 2; ++j) {
      const int f = tid + j * 512;
      const int r = f >> 4;
      const int c = (f & 15) * 8;
      u16x8 w;
      w[0] = f2bf(sx[j * 2].x);     w[1] = f2bf(sx[j * 2].y);
      w[2] = f2bf(sx[j * 2].z);     w[3] = f2bf(sx[j * 2].w);
      w[4] = f2bf(sx[j * 2 + 1].x); w[5] = f2bf(sx[j * 2 + 1].y);
      w[6] = f2bf(sx[j * 2 + 1].z); w[7] = f2bf(sx[j * 2 + 1].w);
      *(u16x8*)&ab[r * ASTRIDE + c] = w;
      u16x8 v;
      v[0] = f2bf(sh[j * 2].x);     v[1] = f2bf(sh[j * 2].y);
      v[2] = f2bf(sh[j * 2].z);     v[3] = f2bf(sh[j * 2].w);
      v[4] = f2bf(sh[j * 2 + 1].x); v[5] = f2bf(sh[j * 2 + 1].y);
      v[6] = f2bf(sh[j * 2 + 1].z); v[7] = f2bf(sh[j * 2 + 1].w);
      *(u16x8*)&ab[r * ASTRIDE + 128 + c] = v;
    }

    __syncthreads();  // ab ready; double-buffer makes this the ONLY barrier

    // ---- issue next tile's prefetches NOW (after the barrier drain point),
    //      so they stay in flight across the whole compute window ----
    if (it + 1 < NITER) {
      const int nrow0 = row0 + NBLK * 64;
      issue_loads(nrow0);
      issue_cv(nrow0, cvW);
    }

    // ---- 4 M-tiles: MFMA all 4 gates, fused LSTM epilogue ----
    const int rb = row0 + (lane >> 4) * 4;
#pragma unroll
    for (int mt = 0; mt < 4; ++mt) {
      f32x4 acc0 = {0.f, 0.f, 0.f, 0.f};
      f32x4 acc1 = acc0, acc2 = acc0, acc3 = acc0;
#pragma unroll
      for (int kk = 0; kk < 8; ++kk) {
        bf16x8 a = *(const bf16x8*)&ab[(mt * 16 + lrow) * ASTRIDE + kk * 32 + lk];
        acc0 = __builtin_amdgcn_mfma_f32_16x16x32_bf16(a, wf[0][kk], acc0, 0, 0, 0);
        acc1 = __builtin_amdgcn_mfma_f32_16x16x32_bf16(a, wf[1][kk], acc1, 0, 0, 0);
        acc2 = __builtin_amdgcn_mfma_f32_16x16x32_bf16(a, wf[2][kk], acc2, 0, 0, 0);
        acc3 = __builtin_amdgcn_mfma_f32_16x16x32_bf16(a, wf[3][kk], acc3, 0, 0, 0);
      }
      const int rbase = rb + mt * 16;
#pragma unroll
      for (int j = 0; j < 4; ++j) {
        const int rg = rbase + j;
        const float cprev = cvR[mt * 4 + j];
        const float it_ = sigm(acc0[j]);
        const float ft = sigm(acc1[j]);
        const float ot = sigm(acc2[j]);
        const float gt = ftanh(acc3[j]);
        const float ct = ft * cprev + it_ * gt;
        const float ht = ot * ftanh(ct);
        Out[(size_t)rg * 128 + hcol] = ht;
        Out[BH + (size_t)rg * 128 + hcol] = ct;
      }
    }
  };

  // ---- prologue: prefetch tile 0 ----
  const int row00 = blockIdx.x * 64;
  issue_loads(row00);
  issue_cv(row00, cv0);

  // manual unroll-by-2 so buffer parity and cv ping-pong are compile-time
  for (int it = 0; it < NITER; it += 2) {
    body(it, &Abuf[0][0], cv0, cv1);
    body(it + 1, &Abuf[1][0], cv1, cv0);
  }
}

extern "C" void kernel_launch(void* const* d_in, const int* in_sizes, int n_in,
                              void* d_out, int out_size, void* d_ws, size_t ws_size,
                              hipStream_t stream) {
  (void)in_sizes; (void)n_in; (void)out_size; (void)d_ws; (void)ws_size;
  lstm_fused<<<NBLK, 512, 0, stream>>>(
      (const float*)d_in[0], (const float*)d_in[1], (const float*)d_in[2],
      (const float*)d_in[3], (const float*)d_in[4], (const float*)d_in[5],
      (const float*)d_in[6], (const float*)d_in[7], (const float*)d_in[8],
      (const float*)d_in[9], (const float*)d_in[10],
      (float*)d_out);
}

// Round 4
// 180.636 us; speedup vs baseline: 3.2284x; 3.2284x over previous
//
#include <hip/hip_runtime.h>

#define BATCH 262144
#define NBLK 512
#define NITER 8           // 4096 tiles / 512 blocks (2 blocks/CU)
#define ASTRIDE 264       // 528B row stride
#define BH 33554432       // B*H

typedef __attribute__((ext_vector_type(8))) short bf16x8;
typedef __attribute__((ext_vector_type(4))) float f32x4;
typedef __attribute__((ext_vector_type(8))) unsigned short u16x8;

__device__ __forceinline__ unsigned short f2bf(float f) {
  unsigned int u = __float_as_uint(f);
  u += 0x7fffu + ((u >> 16) & 1u);  // round-to-nearest-even
  return (unsigned short)(u >> 16);
}

__device__ __forceinline__ float fexp(float x) { return __builtin_amdgcn_exp2f(x * 1.44269504f); }
__device__ __forceinline__ float sigm(float x) { return __builtin_amdgcn_rcpf(1.f + fexp(-x)); }
__device__ __forceinline__ float ftanh(float x) { return 1.f - 2.f * __builtin_amdgcn_rcpf(1.f + fexp(2.f * x)); }

__global__ __launch_bounds__(512, 2) void lstm_fused(
    const float* __restrict__ X, const float* __restrict__ H0, const float* __restrict__ C0,
    const float* __restrict__ Wii, const float* __restrict__ Whi,
    const float* __restrict__ Wif, const float* __restrict__ Whf,
    const float* __restrict__ Wio, const float* __restrict__ Who,
    const float* __restrict__ Wig, const float* __restrict__ Whg,
    float* __restrict__ Out) {
  __shared__ __align__(16) unsigned short Abuf[2][64 * ASTRIDE];

  const int tid = threadIdx.x;
  const int wave = tid >> 6;
  const int lane = tid & 63;
  const int lrow = lane & 15;
  const int lk = (lane >> 4) * 8;       // k sub-offset within a 32-wide K tile
  const int hcol = wave * 16 + lrow;    // hidden column this lane produces
  const int r0 = tid >> 4;              // staging row (0..31), +32 for 2nd chunk
  const int cc = (tid & 15) * 8;        // staging col (8-float chunk)

  const float* Wxp[4] = {Wii, Wif, Wio, Wig};
  const float* Whp[4] = {Whi, Whf, Who, Whg};

  // ---- load weight fragments once; resident in VGPR/AGPR for the whole kernel ----
  bf16x8 wf[4][8];
#pragma unroll
  for (int g = 0; g < 4; ++g) {
#pragma unroll
    for (int kk = 0; kk < 8; ++kk) {
      const int k = kk * 32 + lk;
      const float* src = (kk < 4) ? (Wxp[g] + hcol * 128 + k)
                                  : (Whp[g] + hcol * 128 + (k - 128));
      float4 lo = *(const float4*)src;
      float4 hi = *(const float4*)(src + 4);
      bf16x8 w;
      w[0] = (short)f2bf(lo.x); w[1] = (short)f2bf(lo.y);
      w[2] = (short)f2bf(lo.z); w[3] = (short)f2bf(lo.w);
      w[4] = (short)f2bf(hi.x); w[5] = (short)f2bf(hi.y);
      w[6] = (short)f2bf(hi.z); w[7] = (short)f2bf(hi.w);
      wf[g][kk] = w;
    }
  }

  // Staging registers (tile t+1 in flight during compute of t) — named, never
  // passed by reference, so they stay in VGPRs.
  float4 sx0, sx1, sx2, sx3, sh0, sh1, sh2, sh3;
  float cv0[16], cv1[16];

#define ISSUE_LOADS(ROW0) do {                                           \
    const float* px_ = X + (size_t)((ROW0) + r0) * 128 + cc;             \
    sx0 = *(const float4*)px_;  sx1 = *(const float4*)(px_ + 4);         \
    const float* ph_ = H0 + (size_t)((ROW0) + r0) * 128 + cc;            \
    sh0 = *(const float4*)ph_;  sh1 = *(const float4*)(ph_ + 4);         \
    const float* qx_ = px_ + 32 * 128;                                   \
    sx2 = *(const float4*)qx_;  sx3 = *(const float4*)(qx_ + 4);         \
    const float* qh_ = ph_ + 32 * 128;                                   \
    sh2 = *(const float4*)qh_;  sh3 = *(const float4*)(qh_ + 4);         \
  } while (0)

#define ISSUE_CV(ROW0, CV) do {                                          \
    const int rbv_ = (ROW0) + (lane >> 4) * 4;                           \
    _Pragma("unroll")                                                    \
    for (int mt_ = 0; mt_ < 4; ++mt_)                                    \
      _Pragma("unroll")                                                  \
      for (int j_ = 0; j_ < 4; ++j_)                                     \
        CV[mt_ * 4 + j_] = C0[(size_t)(rbv_ + mt_ * 16 + j_) * 128 + hcol]; \
  } while (0)

#define CVT8(DST, A, B) do {                                             \
    u16x8 t_;                                                            \
    t_[0] = f2bf((A).x); t_[1] = f2bf((A).y);                            \
    t_[2] = f2bf((A).z); t_[3] = f2bf((A).w);                            \
    t_[4] = f2bf((B).x); t_[5] = f2bf((B).y);                            \
    t_[6] = f2bf((B).z); t_[7] = f2bf((B).w);                            \
    *(u16x8*)(DST) = t_;                                                 \
  } while (0)

#define BODY(IT, AB, CVR, CVW) do {                                      \
    const int row0_ = (blockIdx.x + (IT) * NBLK) * 64;                   \
    /* staged regs -> LDS (bf16), 16B writes */                          \
    CVT8(&(AB)[r0 * ASTRIDE + cc], sx0, sx1);                            \
    CVT8(&(AB)[r0 * ASTRIDE + 128 + cc], sh0, sh1);                      \
    CVT8(&(AB)[(r0 + 32) * ASTRIDE + cc], sx2, sx3);                     \
    CVT8(&(AB)[(r0 + 32) * ASTRIDE + 128 + cc], sh2, sh3);               \
    __syncthreads();  /* single barrier per iter (double buffer) */      \
    /* prefetches issued AFTER the barrier drain point: they stay in */  \
    /* flight across the whole compute window below */                   \
    if ((IT) + 1 < NITER) {                                              \
      ISSUE_LOADS(row0_ + NBLK * 64);                                    \
      ISSUE_CV(row0_ + NBLK * 64, CVW);                                  \
    }                                                                    \
    const int rb_ = row0_ + (lane >> 4) * 4;                             \
    _Pragma("unroll")                                                    \
    for (int mt = 0; mt < 4; ++mt) {                                     \
      f32x4 a0 = {0.f, 0.f, 0.f, 0.f}, a1 = a0, a2 = a0, a3 = a0;        \
      _Pragma("unroll")                                                  \
      for (int kk = 0; kk < 8; ++kk) {                                   \
        bf16x8 a = *(const bf16x8*)&(AB)[(mt * 16 + lrow) * ASTRIDE + kk * 32 + lk]; \
        a0 = __builtin_amdgcn_mfma_f32_16x16x32_bf16(a, wf[0][kk], a0, 0, 0, 0); \
        a1 = __builtin_amdgcn_mfma_f32_16x16x32_bf16(a, wf[1][kk], a1, 0, 0, 0); \
        a2 = __builtin_amdgcn_mfma_f32_16x16x32_bf16(a, wf[2][kk], a2, 0, 0, 0); \
        a3 = __builtin_amdgcn_mfma_f32_16x16x32_bf16(a, wf[3][kk], a3, 0, 0, 0); \
      }                                                                  \
      _Pragma("unroll")                                                  \
      for (int j = 0; j < 4; ++j) {                                      \
        const int rg = rb_ + mt * 16 + j;                                \
        const float itv = sigm(a0[j]);                                   \
        const float ftv = sigm(a1[j]);                                   \
        const float otv = sigm(a2[j]);                                   \
        const float gtv = ftanh(a3[j]);                                  \
        const float ctv = ftv * (CVR)[mt * 4 + j] + itv * gtv;           \
        const float htv = otv * ftanh(ctv);                              \
        Out[(size_t)rg * 128 + hcol] = htv;                              \
        Out[BH + (size_t)rg * 128 + hcol] = ctv;                         \
      }                                                                  \
    }                                                                    \
  } while (0)

  // ---- prologue: prefetch tile 0 ----
  ISSUE_LOADS(blockIdx.x * 64);
  ISSUE_CV(blockIdx.x * 64, cv0);

  // unroll-by-2: buffer parity and cv ping-pong are compile-time
  for (int it = 0; it < NITER; it += 2) {
    BODY(it, &Abuf[0][0], cv0, cv1);
    BODY(it + 1, &Abuf[1][0], cv1, cv0);
  }

#undef ISSUE_LOADS
#undef ISSUE_CV
#undef CVT8
#undef BODY
}

extern "C" void kernel_launch(void* const* d_in, const int* in_sizes, int n_in,
                              void* d_out, int out_size, void* d_ws, size_t ws_size,
                              hipStream_t stream) {
  (void)in_sizes; (void)n_in; (void)out_size; (void)d_ws; (void)ws_size;
  lstm_fused<<<NBLK, 512, 0, stream>>>(
      (const float*)d_in[0], (const float*)d_in[1], (const float*)d_in[2],
      (const float*)d_in[3], (const float*)d_in[4], (const float*)d_in[5],
      (const float*)d_in[6], (const float*)d_in[7], (const float*)d_in[8],
      (const float*)d_in[9], (const float*)d_in[10],
      (float*)d_out);
}

// Round 5
// 160.388 us; speedup vs baseline: 3.6360x; 1.1262x over previous
//
#include <hip/hip_runtime.h>

#define BATCH 262144
#define NBLK 256
#define NITER 16          // 4096 tiles / 256 blocks (weights loaded once per CU)
#define ASTRIDE 264       // 528B row stride
#define BH 33554432       // B*H

typedef __attribute__((ext_vector_type(8))) short bf16x8;
typedef __attribute__((ext_vector_type(4))) float f32x4;
typedef __attribute__((ext_vector_type(8))) unsigned short u16x8;

__device__ __forceinline__ unsigned short f2bf(float f) {
  unsigned int u = __float_as_uint(f);
  u += 0x7fffu + ((u >> 16) & 1u);  // round-to-nearest-even
  return (unsigned short)(u >> 16);
}

__device__ __forceinline__ float fexp(float x) { return __builtin_amdgcn_exp2f(x * 1.44269504f); }
__device__ __forceinline__ float sigm(float x) { return __builtin_amdgcn_rcpf(1.f + fexp(-x)); }
__device__ __forceinline__ float ftanh(float x) { return 1.f - 2.f * __builtin_amdgcn_rcpf(1.f + fexp(2.f * x)); }

__global__ __launch_bounds__(512, 2) void lstm_fused(
    const float* __restrict__ X, const float* __restrict__ H0, const float* __restrict__ C0,
    const float* __restrict__ Wii, const float* __restrict__ Whi,
    const float* __restrict__ Wif, const float* __restrict__ Whf,
    const float* __restrict__ Wio, const float* __restrict__ Who,
    const float* __restrict__ Wig, const float* __restrict__ Whg,
    float* __restrict__ Out) {
  __shared__ __align__(16) unsigned short Abuf[2][64 * ASTRIDE];

  const int tid = threadIdx.x;
  const int wave = tid >> 6;
  const int lane = tid & 63;
  const int lrow = lane & 15;
  const int lk = (lane >> 4) * 8;       // k sub-offset within a 32-wide K tile
  const int hcol = wave * 16 + lrow;    // hidden column this lane produces
  const int r0 = tid >> 4;              // staging row (0..31), +32 for 2nd chunk
  const int cc = (tid & 15) * 8;        // staging col (8-float chunk)

  const float* Wxp[4] = {Wii, Wif, Wio, Wig};
  const float* Whp[4] = {Whi, Whf, Who, Whg};

  // ---- load weight fragments once; resident in VGPR/AGPR for the whole kernel ----
  bf16x8 wf[4][8];
#pragma unroll
  for (int g = 0; g < 4; ++g) {
#pragma unroll
    for (int kk = 0; kk < 8; ++kk) {
      const int k = kk * 32 + lk;
      const float* src = (kk < 4) ? (Wxp[g] + hcol * 128 + k)
                                  : (Whp[g] + hcol * 128 + (k - 128));
      float4 lo = *(const float4*)src;
      float4 hi = *(const float4*)(src + 4);
      bf16x8 w;
      w[0] = (short)f2bf(lo.x); w[1] = (short)f2bf(lo.y);
      w[2] = (short)f2bf(lo.z); w[3] = (short)f2bf(lo.w);
      w[4] = (short)f2bf(hi.x); w[5] = (short)f2bf(hi.y);
      w[6] = (short)f2bf(hi.z); w[7] = (short)f2bf(hi.w);
      wf[g][kk] = w;
    }
  }

  // Staging registers (tile t+1 in flight during compute of t) — named scalars,
  // never passed by reference, so they stay in VGPRs.
  float4 sx0, sx1, sx2, sx3, sh0, sh1, sh2, sh3;
  float cv[16];  // current tile's C_prev; statically indexed everywhere

#define ISSUE_LOADS(ROW0) do {                                           \
    const float* px_ = X + (size_t)((ROW0) + r0) * 128 + cc;             \
    sx0 = *(const float4*)px_;  sx1 = *(const float4*)(px_ + 4);         \
    const float* ph_ = H0 + (size_t)((ROW0) + r0) * 128 + cc;            \
    sh0 = *(const float4*)ph_;  sh1 = *(const float4*)(ph_ + 4);         \
    const float* qx_ = px_ + 32 * 128;                                   \
    sx2 = *(const float4*)qx_;  sx3 = *(const float4*)(qx_ + 4);         \
    const float* qh_ = ph_ + 32 * 128;                                   \
    sh2 = *(const float4*)qh_;  sh3 = *(const float4*)(qh_ + 4);         \
  } while (0)

#define ISSUE_CV(ROW0) do {                                              \
    const int rbv_ = (ROW0) + (lane >> 4) * 4;                           \
    _Pragma("unroll")                                                    \
    for (int mt_ = 0; mt_ < 4; ++mt_)                                    \
      _Pragma("unroll")                                                  \
      for (int j_ = 0; j_ < 4; ++j_)                                     \
        cv[mt_ * 4 + j_] = C0[(size_t)(rbv_ + mt_ * 16 + j_) * 128 + hcol]; \
  } while (0)

#define CVT8(DST, A, B) do {                                             \
    u16x8 t_;                                                            \
    t_[0] = f2bf((A).x); t_[1] = f2bf((A).y);                            \
    t_[2] = f2bf((A).z); t_[3] = f2bf((A).w);                            \
    t_[4] = f2bf((B).x); t_[5] = f2bf((B).y);                            \
    t_[6] = f2bf((B).z); t_[7] = f2bf((B).w);                            \
    *(u16x8*)(DST) = t_;                                                 \
  } while (0)

#define BODY(IT, AB) do {                                                \
    const int row0_ = (blockIdx.x + (IT) * NBLK) * 64;                   \
    /* staged regs -> LDS (bf16), 16B writes */                          \
    CVT8(&(AB)[r0 * ASTRIDE + cc], sx0, sx1);                            \
    CVT8(&(AB)[r0 * ASTRIDE + 128 + cc], sh0, sh1);                      \
    CVT8(&(AB)[(r0 + 32) * ASTRIDE + cc], sx2, sx3);                     \
    CVT8(&(AB)[(r0 + 32) * ASTRIDE + 128 + cc], sh2, sh3);               \
    __syncthreads();  /* single barrier per iter (double buffer) */      \
    /* cv first (oldest in vmcnt FIFO: epilogue wait won't chain on the */\
    /* younger X/H prefetch), then next tile's X/H — all in flight */    \
    /* across the MFMA window below */                                   \
    ISSUE_CV(row0_);                                                     \
    if ((IT) + 1 < NITER) ISSUE_LOADS(row0_ + NBLK * 64);                \
    const int rb_ = row0_ + (lane >> 4) * 4;                             \
    _Pragma("unroll")                                                    \
    for (int mt = 0; mt < 4; ++mt) {                                     \
      f32x4 a0 = {0.f, 0.f, 0.f, 0.f}, a1 = a0, a2 = a0, a3 = a0;        \
      _Pragma("unroll")                                                  \
      for (int kk = 0; kk < 8; ++kk) {                                   \
        bf16x8 a = *(const bf16x8*)&(AB)[(mt * 16 + lrow) * ASTRIDE + kk * 32 + lk]; \
        a0 = __builtin_amdgcn_mfma_f32_16x16x32_bf16(a, wf[0][kk], a0, 0, 0, 0); \
        a1 = __builtin_amdgcn_mfma_f32_16x16x32_bf16(a, wf[1][kk], a1, 0, 0, 0); \
        a2 = __builtin_amdgcn_mfma_f32_16x16x32_bf16(a, wf[2][kk], a2, 0, 0, 0); \
        a3 = __builtin_amdgcn_mfma_f32_16x16x32_bf16(a, wf[3][kk], a3, 0, 0, 0); \
      }                                                                  \
      _Pragma("unroll")                                                  \
      for (int j = 0; j < 4; ++j) {                                      \
        const int rg = rb_ + mt * 16 + j;                                \
        const float itv = sigm(a0[j]);                                   \
        const float ftv = sigm(a1[j]);                                   \
        const float otv = sigm(a2[j]);                                   \
        const float gtv = ftanh(a3[j]);                                  \
        const float ctv = ftv * cv[mt * 4 + j] + itv * gtv;              \
        const float htv = otv * ftanh(ctv);                              \
        Out[(size_t)rg * 128 + hcol] = htv;                              \
        Out[BH + (size_t)rg * 128 + hcol] = ctv;                         \
      }                                                                  \
    }                                                                    \
  } while (0)

  // ---- prologue: prefetch tile 0's X/H ----
  ISSUE_LOADS(blockIdx.x * 64);

  // unroll-by-2: buffer parity is compile-time
  for (int it = 0; it < NITER; it += 2) {
    BODY(it, &Abuf[0][0]);
    BODY(it + 1, &Abuf[1][0]);
  }

#undef ISSUE_LOADS
#undef ISSUE_CV
#undef CVT8
#undef BODY
}

extern "C" void kernel_launch(void* const* d_in, const int* in_sizes, int n_in,
                              void* d_out, int out_size, void* d_ws, size_t ws_size,
                              hipStream_t stream) {
  (void)in_sizes; (void)n_in; (void)out_size; (void)d_ws; (void)ws_size;
  lstm_fused<<<NBLK, 512, 0, stream>>>(
      (const float*)d_in[0], (const float*)d_in[1], (const float*)d_in[2],
      (const float*)d_in[3], (const float*)d_in[4], (const float*)d_in[5],
      (const float*)d_in[6], (const float*)d_in[7], (const float*)d_in[8],
      (const float*)d_in[9], (const float*)d_in[10],
      (float*)d_out);
}